// Round 1
// baseline (1921.016 us; speedup 1.0000x reference)
//
#include <hip/hip_runtime.h>

#define TLEN 512
#define FIN 16

__device__ __forceinline__ float sigm(float x) { return 1.0f / (1.0f + __expf(-x)); }
__device__ __forceinline__ float tanh_f(float x) {
  x = fminf(fmaxf(x, -15.0f), 15.0f);
  float e = __expf(2.0f * x);
  return (e - 1.0f) / (e + 1.0f);
}

// Block = 256 threads (4 waves) handles 2 batch elements for all T steps.
// Weights: r0,k0,k1,r1 columns register-cached per thread; k2,r2,k3,r3 in LDS.
__global__ __launch_bounds__(256, 1)
void rnn_fused(const float* __restrict__ x, const float* __restrict__ emb,
               const float* __restrict__ k0, const float* __restrict__ r0,
               const float* __restrict__ bi0, const float* __restrict__ bh0,
               const float* __restrict__ k1, const float* __restrict__ r1,
               const float* __restrict__ bi1, const float* __restrict__ bh1,
               const float* __restrict__ k2w, const float* __restrict__ r2w,
               const float* __restrict__ bi2, const float* __restrict__ bh2,
               const float* __restrict__ k3w, const float* __restrict__ r3w,
               const float* __restrict__ bi3, const float* __restrict__ bh3,
               const float* __restrict__ w1, const float* __restrict__ b1,
               const float* __restrict__ w2, const float* __restrict__ b2,
               const float* __restrict__ vv, const float* __restrict__ bv,
               const float* __restrict__ wd, const float* __restrict__ bd,
               float* __restrict__ out, float* __restrict__ obuf)
{
  __shared__ float s_mats[12288];                // k2|r2|k3|r3 ; epilogue alias
  __shared__ __align__(16) float s_h0[64][2];
  __shared__ __align__(16) float s_h1[32][2];
  __shared__ __align__(16) float s_h2[32][2];
  __shared__ __align__(16) float s_h3[32][2];
  __shared__ float s_g[2][4][64];                // gate scratch: sz,sr,xh,hhp
  __shared__ __align__(16) float s_inp[2][24][2];// double-buffered input rows

  const int tid = threadIdx.x;
  const int bb0 = blockIdx.x * 2;

  float* s_k2 = s_mats;
  float* s_r2 = s_mats + 3072;
  float* s_k3 = s_mats + 6144;
  float* s_r3 = s_mats + 9216;

  for (int i = tid; i < 3072; i += 256) {
    s_k2[i] = k2w[i]; s_r2[i] = r2w[i]; s_k3[i] = k3w[i]; s_r3[i] = r3w[i];
  }
  if (tid < 64) { s_h0[tid][0] = 0.f; s_h0[tid][1] = 0.f; }
  if (tid < 32) {
    s_h1[tid][0] = 0.f; s_h1[tid][1] = 0.f;
    s_h2[tid][0] = 0.f; s_h2[tid][1] = 0.f;
    s_h3[tid][0] = 0.f; s_h3[tid][1] = 0.f;
  }
  if (tid < 2) { s_inp[0][19][tid] = 0.f; s_inp[1][19][tid] = 0.f; }

  // register-cached weight columns (threads 0..191)
  float w0[64], k0c[20], wk1[64], wr1[32];
  float bi0c=0,bh0c=0,bi1c=0,bh1c=0,bi2c=0,bh2c=0,bi3c=0,bh3c=0;
  if (tid < 192) {
    #pragma unroll
    for (int j = 0; j < 64; ++j) w0[j] = r0[j*192 + tid];
    #pragma unroll
    for (int j = 0; j < 19; ++j) k0c[j] = k0[j*192 + tid];
    k0c[19] = 0.f;
    bi0c = bi0[tid]; bh0c = bh0[tid];
    const int o1 = tid % 96;
    #pragma unroll
    for (int j = 0; j < 64; ++j) wk1[j] = k1[j*96 + o1];
    #pragma unroll
    for (int j = 0; j < 32; ++j) wr1[j] = r1[j*96 + o1];
    bi1c = bi1[o1]; bh1c = bh1[o1];
    bi2c = bi2[o1]; bh2c = bh2[o1];
    bi3c = bi3[o1]; bh3c = bh3[o1];
  }

  auto load_inp = [&](int ts, int par) {
    const int lane = tid - 192;
    if (lane < 32) {
      const int b = lane >> 4, f = lane & 15;
      const float val = x[((size_t)(bb0 + b) * TLEN + ts) * FIN + f];
      if (f == 0) s_inp[par][0][b] = val;
      else if (f == 1) {
        const int id = (int)val;
        const float* e = emb + id * 4;
        s_inp[par][15][b] = e[0]; s_inp[par][16][b] = e[1];
        s_inp[par][17][b] = e[2]; s_inp[par][18][b] = e[3];
      } else s_inp[par][f - 1][b] = val;
    }
  };

  if (tid >= 192) load_inp(0, 0);
  __syncthreads();

  for (int ts = 0; ts < TLEN; ++ts) {
    const int par = ts & 1;
    // ---- L0 gates: thread t<192 owns output o=t, both batches
    if (tid < 192) {
      float a0=0, a1=0, a2=0, a3=0;
      #pragma unroll
      for (int j = 0; j < 20; j += 2) {
        const float4 i4 = *(const float4*)&s_inp[par][j][0];
        a0 += k0c[j]   * i4.x;  a1 += k0c[j]   * i4.y;
        a2 += k0c[j+1] * i4.z;  a3 += k0c[j+1] * i4.w;
      }
      const float xpA = bi0c + a0 + a2;
      const float xpB = bi0c + a1 + a3;
      float c0=0, c1=0, c2=0, c3=0;
      #pragma unroll
      for (int j = 0; j < 64; j += 2) {
        const float4 h4 = *(const float4*)&s_h0[j][0];
        c0 += w0[j]   * h4.x;  c1 += w0[j]   * h4.y;
        c2 += w0[j+1] * h4.z;  c3 += w0[j+1] * h4.w;
      }
      const float hpA = bh0c + c0 + c2;
      const float hpB = bh0c + c1 + c3;
      const int g = tid >> 6, u = tid & 63;
      if (g < 2) {
        s_g[0][g][u] = xpA + hpA;
        s_g[1][g][u] = xpB + hpB;
      } else {
        s_g[0][2][u] = xpA; s_g[0][3][u] = hpA;
        s_g[1][2][u] = xpB; s_g[1][3][u] = hpB;
      }
    } else if (ts + 1 < TLEN) {
      load_inp(ts + 1, par ^ 1);   // wave 3 prefetches next input row
    }
    __syncthreads();
    // ---- L0 update
    if (tid < 128) {
      const int u = tid & 63, b = tid >> 6;
      const float z = sigm(s_g[b][0][u]);
      const float r = sigm(s_g[b][1][u]);
      const float hh = tanh_f(s_g[b][2][u] + r * s_g[b][3][u]);
      s_h0[u][b] = z * s_h0[u][b] + (1.f - z) * hh;
    }
    __syncthreads();
    // ---- L1 gates: thread t<192: o1 = t%96, b = t/96
    if (tid < 192) {
      const int b = tid / 96, o1 = tid % 96;
      float xa=0, xb=0;
      #pragma unroll
      for (int j = 0; j < 64; j += 2) {
        xa += wk1[j]   * s_h0[j][b];
        xb += wk1[j+1] * s_h0[j+1][b];
      }
      float ha=0, hb=0;
      #pragma unroll
      for (int j = 0; j < 32; j += 2) {
        ha += wr1[j]   * s_h1[j][b];
        hb += wr1[j+1] * s_h1[j+1][b];
      }
      const float xp = bi1c + xa + xb;
      const float hp = bh1c + ha + hb;
      const int g = o1 >> 5, u = o1 & 31;
      if (g < 2) s_g[b][g][u] = xp + hp;
      else { s_g[b][2][u] = xp; s_g[b][3][u] = hp; }
    }
    __syncthreads();
    // ---- L1 update
    if (tid < 64) {
      const int u = tid & 31, b = tid >> 5;
      const float z = sigm(s_g[b][0][u]);
      const float r = sigm(s_g[b][1][u]);
      const float hh = tanh_f(s_g[b][2][u] + r * s_g[b][3][u]);
      s_h1[u][b] = z * s_h1[u][b] + (1.f - z) * hh;
    }
    __syncthreads();
    // ---- L2 gates (weights from LDS, lane-contiguous reads)
    if (tid < 192) {
      const int b = tid / 96, o1 = tid % 96;
      float xa=0, xb=0, ha=0, hb=0;
      #pragma unroll
      for (int j = 0; j < 32; j += 2) {
        xa += s_k2[j*96 + o1]     * s_h1[j][b];
        xb += s_k2[(j+1)*96 + o1] * s_h1[j+1][b];
        ha += s_r2[j*96 + o1]     * s_h2[j][b];
        hb += s_r2[(j+1)*96 + o1] * s_h2[j+1][b];
      }
      const float xp = bi2c + xa + xb;
      const float hp = bh2c + ha + hb;
      const int g = o1 >> 5, u = o1 & 31;
      if (g < 2) s_g[b][g][u] = xp + hp;
      else { s_g[b][2][u] = xp; s_g[b][3][u] = hp; }
    }
    __syncthreads();
    // ---- L2 update
    if (tid < 64) {
      const int u = tid & 31, b = tid >> 5;
      const float z = sigm(s_g[b][0][u]);
      const float r = sigm(s_g[b][1][u]);
      const float hh = tanh_f(s_g[b][2][u] + r * s_g[b][3][u]);
      s_h2[u][b] = z * s_h2[u][b] + (1.f - z) * hh;
    }
    __syncthreads();
    // ---- L3 gates
    if (tid < 192) {
      const int b = tid / 96, o1 = tid % 96;
      float xa=0, xb=0, ha=0, hb=0;
      #pragma unroll
      for (int j = 0; j < 32; j += 2) {
        xa += s_k3[j*96 + o1]     * s_h2[j][b];
        xb += s_k3[(j+1)*96 + o1] * s_h2[j+1][b];
        ha += s_r3[j*96 + o1]     * s_h3[j][b];
        hb += s_r3[(j+1)*96 + o1] * s_h3[j+1][b];
      }
      const float xp = bi3c + xa + xb;
      const float hp = bh3c + ha + hb;
      const int g = o1 >> 5, u = o1 & 31;
      if (g < 2) s_g[b][g][u] = xp + hp;
      else { s_g[b][2][u] = xp; s_g[b][3][u] = hp; }
    }
    __syncthreads();
    // ---- L3 update + stream output row
    if (tid < 64) {
      const int u = tid & 31, b = tid >> 5;
      const float z = sigm(s_g[b][0][u]);
      const float r = sigm(s_g[b][1][u]);
      const float hh = tanh_f(s_g[b][2][u] + r * s_g[b][3][u]);
      const float hn = z * s_h3[u][b] + (1.f - z) * hh;
      s_h3[u][b] = hn;
      obuf[((size_t)(bb0 + b) * TLEN + ts) * 32 + u] = hn;
    }
    __syncthreads();
  }

  // ================= attention epilogue (aliases s_mats) =================
  float* e_w1  = s_mats;          // 1024
  float* e_w2  = s_mats + 1024;   // 1024
  float* e_sc  = s_mats + 2048;   // 1024 = 2 x 512 scores
  float* e_hw2 = s_mats + 3072;   // 64
  float* e_ctx = s_mats + 3136;   // 64
  float* e_v   = s_mats + 3200;   // 32
  float* e_b1  = s_mats + 3232;   // 32
  float* e_wd  = s_mats + 3264;   // 64

  for (int i = tid; i < 1024; i += 256) { e_w1[i] = w1[i]; e_w2[i] = w2[i]; }
  if (tid < 32) { e_v[tid] = vv[tid]; e_b1[tid] = b1[tid]; }
  if (tid < 64) e_wd[tid] = wd[tid];
  __syncthreads();

  if (tid < 64) {            // hw2 = hT @ w2 + b2
    const int u = tid & 31, b = tid >> 5;
    float s = b2[u];
    #pragma unroll
    for (int j = 0; j < 32; ++j) s += s_h3[j][b] * e_w2[j*32 + u];
    e_hw2[b*32 + u] = s;
  }
  __syncthreads();

  for (int c = 0; c < 4; ++c) {   // scores: 1024 tasks (2 batches x 512 t)
    const int idx = c * 256 + tid;
    const int b = idx >> 9, t2 = idx & 511;
    const float* row = obuf + ((size_t)(bb0 + b) * TLEN + t2) * 32;
    float rr[32];
    #pragma unroll
    for (int j = 0; j < 32; j += 4) {
      const float4 r4 = *(const float4*)&row[j];
      rr[j] = r4.x; rr[j+1] = r4.y; rr[j+2] = r4.z; rr[j+3] = r4.w;
    }
    float sc = 0.f;
    for (int u = 0; u < 32; ++u) {
      float q = e_b1[u] + e_hw2[b*32 + u];
      #pragma unroll
      for (int j = 0; j < 32; ++j) q += rr[j] * e_w1[j*32 + u];
      sc += tanh_f(q) * e_v[u];
    }
    e_sc[idx] = sc;   // bv omitted: constant shift cancels in softmax
  }
  __syncthreads();

  {  // softmax over T per batch: wave 0 -> b=0, wave 1 -> b=1
    const int wid = tid >> 6, lane = tid & 63;
    if (wid < 2) {
      const int b = wid;
      float sv[8];
      float m = -1e30f;
      #pragma unroll
      for (int k = 0; k < 8; ++k) { sv[k] = e_sc[b*512 + lane + 64*k]; m = fmaxf(m, sv[k]); }
      #pragma unroll
      for (int off = 32; off > 0; off >>= 1) m = fmaxf(m, __shfl_xor(m, off));
      float ss = 0.f;
      #pragma unroll
      for (int k = 0; k < 8; ++k) { sv[k] = __expf(sv[k] - m); ss += sv[k]; }
      #pragma unroll
      for (int off = 32; off > 0; off >>= 1) ss += __shfl_xor(ss, off);
      const float inv = 1.f / ss;
      #pragma unroll
      for (int k = 0; k < 8; ++k) e_sc[b*512 + lane + 64*k] = sv[k] * inv;
    }
  }
  __syncthreads();

  if (tid < 64) {            // ctx = sum_t p_t * out_t  (coalesced across u)
    const int u = tid & 31, b = tid >> 5;
    float acc = 0.f;
    const float* orow = obuf + (size_t)(bb0 + b) * TLEN * 32 + u;
    const float* prow = e_sc + b * 512;
    #pragma unroll 4
    for (int t2 = 0; t2 < 512; ++t2) acc += prow[t2] * orow[(size_t)t2 * 32];
    e_ctx[b*32 + u] = acc;
  }
  __syncthreads();

  if (tid < 2) {             // final 2-class softmax
    const int b = tid;
    float l0 = bd[0], l1 = bd[1];
    #pragma unroll
    for (int u = 0; u < 32; ++u) {
      const float cv = e_ctx[b*32 + u];
      l0 += cv * e_wd[u*2];
      l1 += cv * e_wd[u*2 + 1];
    }
    const float mm = fmaxf(l0, l1);
    const float ex0 = __expf(l0 - mm), ex1 = __expf(l1 - mm);
    const float den = ex0 + ex1;
    out[(bb0 + b)*2 + 0] = ex0 / den;
    out[(bb0 + b)*2 + 1] = ex1 / den;
  }
}

extern "C" void kernel_launch(void* const* d_in, const int* in_sizes, int n_in,
                              void* d_out, int out_size, void* d_ws, size_t ws_size,
                              hipStream_t stream) {
  const float* x   = (const float*)d_in[0];
  const float* emb = (const float*)d_in[1];
  const float* k0  = (const float*)d_in[2];
  const float* r0  = (const float*)d_in[3];
  const float* bi0 = (const float*)d_in[4];
  const float* bh0 = (const float*)d_in[5];
  const float* k1  = (const float*)d_in[6];
  const float* r1  = (const float*)d_in[7];
  const float* bi1 = (const float*)d_in[8];
  const float* bh1 = (const float*)d_in[9];
  const float* k2  = (const float*)d_in[10];
  const float* r2  = (const float*)d_in[11];
  const float* bi2 = (const float*)d_in[12];
  const float* bh2 = (const float*)d_in[13];
  const float* k3  = (const float*)d_in[14];
  const float* r3  = (const float*)d_in[15];
  const float* bi3 = (const float*)d_in[16];
  const float* bh3 = (const float*)d_in[17];
  const float* w1  = (const float*)d_in[18];
  const float* b1  = (const float*)d_in[19];
  const float* w2  = (const float*)d_in[20];
  const float* b2  = (const float*)d_in[21];
  const float* v   = (const float*)d_in[22];
  const float* bv  = (const float*)d_in[23];
  const float* wd  = (const float*)d_in[24];
  const float* bd  = (const float*)d_in[25];

  float* out  = (float*)d_out;
  float* obuf = (float*)d_ws;   // 512*512*32*4 = 33.5 MB < ws_size

  rnn_fused<<<dim3(256), dim3(256), 0, stream>>>(
      x, emb, k0, r0, bi0, bh0, k1, r1, bi1, bh1,
      k2, r2, bi2, bh2, k3, r3, bi3, bh3,
      w1, b1, w2, b2, v, bv, wd, bd, out, obuf);
}